// Round 12
// baseline (184.585 us; speedup 1.0000x reference)
//
#include <hip/hip_runtime.h>
#include <math.h>

#define HH 128
#define BB 2
#define NN 48
#define TT 24
#define MM 192
#define LL 20
#define NT (BB*NN*TT)   /* 2304 */
#define RSQRT_H 0.08838834764831845f  /* 1/sqrt(128) */
#define RADIUS_C 30.0f

struct P {
    const float *astate, *amask, *polylines, *poly_mask;
    const int *ptype, *tlst, *route;
    const float *ae_w0,*ae_b0,*ae_w1,*ae_b1,*ae_w2,*ae_b2;
    const float *mp_w0,*mp_b0,*mp_w1,*mp_b1;
    const float *type_emb,*tl_emb,*route_emb;
    const float *mo_w0,*mo_b0,*mo_w1,*mo_b1;
    const float *mr_w0,*mr_b0,*mr_w1,*mr_b1;
    const float *nr_w0,*nr_b0,*nr_w1,*nr_b1;
    const float *to_w0,*to_b0,*to_w1,*to_b1;
    float *tau,*map_ctx,*nbr_ctx;
    float *a_emb,*map_node,*map_nodeT,*map_center;
};

// ---- k_enc LDS layouts (R10-proven, conflict-free) ----
struct SME { float pts[LL*2]; float h1[LL][HH]; float mx[2][HH]; float hb[HH]; float pr[2][HH]; float hb2[HH]; };
struct SAG { float xin[2][5]; float h1[2][HH]; float h2[2][HH]; float p1[2][2][HH]; };

// ---- fused attn+tau LDS, 4 rows/block, 512 threads (~33 KB) ----
struct SF {
    float4 aq4L[HH];        // [k] -> 4 query rows (persistent through tau)
    float  mctx[4][HH];
    float  nctx[4][HH];
    float  pc[4][4][HH];    // 4-way partial accumulators, reused each phase
    union {
        struct {            // map-attention phase
            float4 w4L[HH];
            float  w1L[HH];
            float4 pS[2][MM];    // rel-score partials (k-halves)
            float4 pD[2][MM];    // dot partials
            float  lg[4][MM];
            float4 p4L[MM];
            float  invL[4];
        } m;
        struct {            // nbr-attention phase
            float  pjL[NN][8];
            float4 wAL[HH];
            float4 wBL[HH];
            float  sPL[8][4][NN];
            float  dPL[8][4][NN];
            float  lgN[4][NN];
            float4 pN[NN];
        } n;
        struct {            // tau phase
            float4 xinT[3*HH];   // [k] -> 4 rows
            float4 h1T[HH];      // [k] -> 4 rows
        } t;
    } u;
};

// ---------------- 1a: map polyline encoder (one bm per block, 256 thr) ----------------
__device__ void do_map_enc(const P& p, SME& s, int bm) {
    int tid = threadIdx.x, pp = tid >> 7, c = tid & 127;
    if (tid < LL*2) s.pts[tid] = p.polylines[(size_t)bm*LL*2 + tid];
    __syncthreads();
    {
        float w0x = p.mp_w0[c], w0y = p.mp_w0[HH + c], b0 = p.mp_b0[c];
        #pragma unroll
        for (int i = 0; i < 10; ++i) {
            int pt_ = pp + 2*i;
            s.h1[pt_][c] = fmaxf(fmaf(s.pts[2*pt_], w0x, fmaf(s.pts[2*pt_+1], w0y, b0)), 0.f);
        }
    }
    if (tid < 2) {
        float sum = 0.f;
        for (int q = 0; q < LL; ++q) sum += s.pts[2*q + tid];
        p.map_center[bm*2 + tid] = sum * (1.0f / LL);
    }
    __syncthreads();
    {
        float acc[10];
        float b1 = p.mp_b1[c];
        #pragma unroll
        for (int i = 0; i < 10; ++i) acc[i] = b1;
        for (int k = 0; k < HH; ++k) {
            float wv = p.mp_w1[k*HH + c];
            #pragma unroll
            for (int i = 0; i < 10; ++i) acc[i] = fmaf(s.h1[pp + 2*i][k], wv, acc[i]);
        }
        float m10 = acc[0];
        #pragma unroll
        for (int i = 1; i < 10; ++i) m10 = fmaxf(m10, acc[i]);
        s.mx[pp][c] = m10;
    }
    __syncthreads();
    if (tid < HH) {
        float hm = fmaxf(fmaxf(s.mx[0][c], s.mx[1][c]), 0.f);
        int pt = p.ptype[bm]; pt = pt < 0 ? 0 : (pt > 3 ? 3 : pt);
        int tv = p.tlst[bm];  tv = tv < 0 ? 0 : (tv > 7 ? 7 : tv);
        int rv = p.route[bm]; rv = rv < 0 ? 0 : (rv > 1 ? 1 : rv);
        hm += p.type_emb[pt*HH + c] + p.tl_emb[tv*HH + c] + p.route_emb[rv*HH + c];
        s.hb[c] = hm;
    }
    __syncthreads();
    {
        float sum = 0.f;
        int k0 = pp*64;
        for (int k = k0; k < k0 + 64; ++k) sum = fmaf(s.hb[k], p.mo_w0[k*HH + c], sum);
        s.pr[pp][c] = sum;
    }
    __syncthreads();
    if (tid < HH) s.hb2[c] = fmaxf(s.pr[0][c] + s.pr[1][c] + p.mo_b0[c], 0.f);
    __syncthreads();
    {
        float sum = 0.f;
        int k0 = pp*64;
        for (int k = k0; k < k0 + 64; ++k) sum = fmaf(s.hb2[k], p.mo_w1[k*HH + c], sum);
        s.pr[pp][c] = sum;
    }
    __syncthreads();
    if (tid < HH) {
        float a3 = s.pr[0][c] + s.pr[1][c] + p.mo_b1[c];
        float mk = (p.poly_mask[bm] > 0.5f) ? 1.f : 0.f;
        float v = a3 * mk;
        p.map_node[(size_t)bm*HH + c] = v;
        int b = bm / MM, m = bm % MM;
        p.map_nodeT[((size_t)b*HH + c)*MM + m] = v;
    }
}

// ---------------- 1b: agent encoder (2 rows per block, 256 thr) ----------------
__device__ void do_agent_enc(const P& p, SAG& s, int r0) {
    int tid = threadIdx.x, h = tid >> 7, c = tid & 127;
    if (tid < 10) s.xin[tid/5][tid%5] = p.astate[(size_t)r0*5 + tid];
    __syncthreads();
    if (h == 0) {
        float b = p.ae_b0[c];
        float w[5];
        #pragma unroll
        for (int i = 0; i < 5; ++i) w[i] = p.ae_w0[i*HH + c];
        #pragma unroll
        for (int r = 0; r < 2; ++r) {
            float v = b;
            #pragma unroll
            for (int i = 0; i < 5; ++i) v = fmaf(s.xin[r][i], w[i], v);
            s.h1[r][c] = fmaxf(v, 0.f);
        }
    }
    __syncthreads();
    {
        float a0 = 0.f, a1 = 0.f;
        int k0 = h*64;
        for (int k = k0; k < k0 + 64; ++k) {
            float wv = p.ae_w1[k*HH + c];
            a0 = fmaf(s.h1[0][k], wv, a0);
            a1 = fmaf(s.h1[1][k], wv, a1);
        }
        s.p1[h][0][c] = a0; s.p1[h][1][c] = a1;
    }
    __syncthreads();
    {
        int r = h;
        s.h2[r][c] = fmaxf(s.p1[0][r][c] + s.p1[1][r][c] + p.ae_b1[c], 0.f);
    }
    __syncthreads();
    {
        float a0 = 0.f, a1 = 0.f;
        int k0 = h*64;
        for (int k = k0; k < k0 + 64; ++k) {
            float wv = p.ae_w2[k*HH + c];
            a0 = fmaf(s.h2[0][k], wv, a0);
            a1 = fmaf(s.h2[1][k], wv, a1);
        }
        s.p1[h][0][c] = a0; s.p1[h][1][c] = a1;
    }
    __syncthreads();
    {
        int r = h;
        int row = r0 + r;
        p.a_emb[(size_t)row*HH + c] = (s.p1[0][r][c] + s.p1[1][r][c] + p.ae_b2[c]) * p.amask[row];
    }
}

// ---------------- kernel A: encoders (384 + 1152 = 1536 blocks) ----------------
__global__ __launch_bounds__(256) void k_enc(P p) {
    __shared__ __align__(16) char smraw[(sizeof(SME) > sizeof(SAG)) ? sizeof(SME) : sizeof(SAG)];
    int task = blockIdx.x;
    if (task < BB*MM) do_map_enc(p, *(SME*)smraw, task);
    else              do_agent_enc(p, *(SAG*)smraw, (task - BB*MM)*2);
}

// ---------------- kernel B: fused map-attn + nbr-attn + tau ----------------
// 576 blocks, 512 thr; block = 4 n-rows at fixed (b,t)
__global__ __launch_bounds__(512) void k_fat(P p) {
    __shared__ __align__(16) SF s;
    int task = blockIdx.x;
    int b    = task / (TT*12);
    int rem  = task % (TT*12);
    int t    = rem / 12;
    int n0   = (rem % 12) * 4;
    int tid  = threadIdx.x;

    int row0 = (b*NN + n0)*TT + t;          // row(r) = row0 + r*TT

    // ---- stage queries (512 = 4*HH exactly) + map weights ----
    {
        int r = tid >> 7, k = tid & 127;
        ((float*)&s.aq4L[k])[r] = p.a_emb[(size_t)(row0 + r*TT)*HH + k];
    }
    if (tid < HH) {
        int k = tid;
        s.u.m.w4L[k] = make_float4(p.mr_w0[k], p.mr_w0[HH+k], p.mr_w0[2*HH+k], p.mr_b0[k]);
        s.u.m.w1L[k] = p.mr_w1[k];
    }

    // per-(m,r) geometry, computed by both k-half groups
    int g  = tid >> 8;      // 0,1: k-half
    int ml = tid & 255;     // lane within group
    float rx[4], ry[4], rd[4];
    if (ml < MM) {
        float mcx = p.map_center[(b*MM + ml)*2];
        float mcy = p.map_center[(b*MM + ml)*2 + 1];
        #pragma unroll
        for (int r = 0; r < 4; ++r) {
            float px = p.astate[(size_t)(row0 + r*TT)*5];
            float py = p.astate[(size_t)(row0 + r*TT)*5 + 1];
            rx[r] = mcx - px; ry[r] = mcy - py;
            rd[r] = sqrtf(rx[r]*rx[r] + ry[r]*ry[r]);
        }
    }
    __syncthreads();

    // ---- map phase A: 2-way k-split, direct L2 reads of mnT ----
    if (ml < MM) {
        const float* mnc = p.map_nodeT + (size_t)b*HH*MM + ml;
        float sacc[4] = {0.f,0.f,0.f,0.f};
        float dt4[4]  = {0.f,0.f,0.f,0.f};
        int k0 = g*64;
        #pragma unroll 4
        for (int kk = 0; kk < 64; ++kk) {
            int k = k0 + kk;
            float4 w  = s.u.m.w4L[k];
            float4 aq = s.aq4L[k];
            float  w1 = s.u.m.w1L[k];
            float  mn = mnc[(size_t)k*MM];
            #pragma unroll
            for (int r = 0; r < 4; ++r) {
                float hv = fmaf(rx[r], w.x, fmaf(ry[r], w.y, fmaf(rd[r], w.z, w.w)));
                sacc[r] = fmaf(fmaxf(hv, 0.f), w1, sacc[r]);
            }
            dt4[0] = fmaf(aq.x, mn, dt4[0]);
            dt4[1] = fmaf(aq.y, mn, dt4[1]);
            dt4[2] = fmaf(aq.z, mn, dt4[2]);
            dt4[3] = fmaf(aq.w, mn, dt4[3]);
        }
        s.u.m.pS[g][ml] = make_float4(sacc[0], sacc[1], sacc[2], sacc[3]);
        s.u.m.pD[g][ml] = make_float4(dt4[0],  dt4[1],  dt4[2],  dt4[3]);
    }
    __syncthreads();
    if (tid < MM) {
        float4 sA = s.u.m.pS[0][tid], sB = s.u.m.pS[1][tid];
        float4 dA = s.u.m.pD[0][tid], dB = s.u.m.pD[1][tid];
        float pm = p.poly_mask[b*MM + tid];
        float b1 = p.mr_b1[0];
        float lg0 = fmaf(dA.x + dB.x, RSQRT_H, sA.x + sB.x + b1);
        float lg1 = fmaf(dA.y + dB.y, RSQRT_H, sA.y + sB.y + b1);
        float lg2 = fmaf(dA.z + dB.z, RSQRT_H, sA.z + sB.z + b1);
        float lg3 = fmaf(dA.w + dB.w, RSQRT_H, sA.w + sB.w + b1);
        bool ok = pm > 0.5f;
        s.u.m.lg[0][tid] = ok ? lg0 : -1e9f;
        s.u.m.lg[1][tid] = ok ? lg1 : -1e9f;
        s.u.m.lg[2][tid] = ok ? lg2 : -1e9f;
        s.u.m.lg[3][tid] = ok ? lg3 : -1e9f;
    }
    __syncthreads();

    // ---- map softmax: waves 0-3 handle rows 0-3 ----
    if (tid < 256) {
        int r = tid >> 6, l = tid & 63;
        float v = fmaxf(fmaxf(s.u.m.lg[r][l], s.u.m.lg[r][l+64]), s.u.m.lg[r][l+128]);
        #pragma unroll
        for (int o = 32; o > 0; o >>= 1) v = fmaxf(v, __shfl_xor(v, o));
        float e0 = expf(s.u.m.lg[r][l] - v);
        float e1 = expf(s.u.m.lg[r][l+64] - v);
        float e2 = expf(s.u.m.lg[r][l+128] - v);
        s.u.m.lg[r][l] = e0; s.u.m.lg[r][l+64] = e1; s.u.m.lg[r][l+128] = e2;
        float sm = e0 + e1 + e2;
        #pragma unroll
        for (int o = 32; o > 0; o >>= 1) sm += __shfl_xor(sm, o);
        if (l == 0) s.u.m.invL[r] = 1.0f / sm;
    }
    __syncthreads();
    if (tid < MM) {
        s.u.m.p4L[tid] = make_float4(s.u.m.lg[0][tid]*s.u.m.invL[0], s.u.m.lg[1][tid]*s.u.m.invL[1],
                                     s.u.m.lg[2][tid]*s.u.m.invL[2], s.u.m.lg[3][tid]*s.u.m.invL[3]);
    }
    __syncthreads();

    // ---- map phase C: 4-way m-split, each map_node load feeds 4 rows ----
    {
        int gq = tid >> 7, c = tid & 127;    // gq in 0..3, 48 m each
        float a0=0.f, a1=0.f, a2=0.f, a3=0.f;
        const float* mnb = p.map_node + ((size_t)b*MM + gq*48)*HH + c;
        for (int m = 0; m < 48; ++m) {
            float mv = mnb[(size_t)m*HH];
            float4 pp4 = s.u.m.p4L[gq*48 + m];
            a0 = fmaf(pp4.x, mv, a0); a1 = fmaf(pp4.y, mv, a1);
            a2 = fmaf(pp4.z, mv, a2); a3 = fmaf(pp4.w, mv, a3);
        }
        s.pc[gq][0][c]=a0; s.pc[gq][1][c]=a1; s.pc[gq][2][c]=a2; s.pc[gq][3][c]=a3;
    }
    __syncthreads();
    {
        int r = tid >> 7, c = tid & 127;
        float v = s.pc[0][r][c] + s.pc[1][r][c] + s.pc[2][r][c] + s.pc[3][r][c];
        s.mctx[r][c] = v;
        p.map_ctx[(size_t)(row0 + r*TT)*HH + c] = v;
    }
    __syncthreads();   // u.m dead

    // ---- nbr phase: stage positions + weights ----
    if (tid < NN) {
        int rj = (b*NN + tid)*TT + t;
        s.u.n.pjL[tid][0] = p.astate[(size_t)rj*5];
        s.u.n.pjL[tid][1] = p.astate[(size_t)rj*5 + 1];
        s.u.n.pjL[tid][2] = p.astate[(size_t)rj*5 + 3];
        s.u.n.pjL[tid][3] = p.astate[(size_t)rj*5 + 4];
        s.u.n.pjL[tid][4] = p.amask[rj];
    }
    if (tid < HH) {
        int k = tid;
        s.u.n.wAL[k] = make_float4(p.nr_w0[k], p.nr_w0[HH+k], p.nr_w0[2*HH+k], p.nr_w0[3*HH+k]);
        s.u.n.wBL[k] = make_float4(p.nr_w0[4*HH+k], p.nr_b0[k], p.nr_w1[k], 0.f);
    }
    __syncthreads();

    // ---- nbr phase A: 8-way k-split (kg), 48 j lanes each ----
    {
        int j  = tid % 48;
        int kg = tid / 48;                   // 0..10, active < 8
        if (kg < 8) {
            float jx = s.u.n.pjL[j][0], jy = s.u.n.pjL[j][1];
            float jvx = s.u.n.pjL[j][2], jvy = s.u.n.pjL[j][3];
            float dx[4], dy[4], dvx[4], dvy[4], dd[4];
            #pragma unroll
            for (int r = 0; r < 4; ++r) {
                int ni = n0 + r;
                dx[r]  = s.u.n.pjL[ni][0] - jx;  dy[r]  = s.u.n.pjL[ni][1] - jy;
                dvx[r] = s.u.n.pjL[ni][2] - jvx; dvy[r] = s.u.n.pjL[ni][3] - jvy;
                dd[r]  = sqrtf(dx[r]*dx[r] + dy[r]*dy[r]);
            }
            const float* aj = p.a_emb + ((size_t)(b*NN + j)*TT + t)*HH;
            float sr[4]  = {0.f,0.f,0.f,0.f};
            float dtn[4] = {0.f,0.f,0.f,0.f};
            int k0 = kg*16;
            #pragma unroll 4
            for (int kk = 0; kk < 16; ++kk) {
                int k = k0 + kk;
                float4 wa = s.u.n.wAL[k], wb = s.u.n.wBL[k];
                float4 aq = s.aq4L[k];
                float  av = aj[k];
                #pragma unroll
                for (int r = 0; r < 4; ++r) {
                    float hv = fmaf(dx[r], wa.x, fmaf(dy[r], wa.y,
                               fmaf(dvx[r], wa.z, fmaf(dvy[r], wa.w,
                               fmaf(dd[r], wb.x, wb.y)))));
                    sr[r] = fmaf(fmaxf(hv, 0.f), wb.z, sr[r]);
                }
                dtn[0] = fmaf(aq.x, av, dtn[0]); dtn[1] = fmaf(aq.y, av, dtn[1]);
                dtn[2] = fmaf(aq.z, av, dtn[2]); dtn[3] = fmaf(aq.w, av, dtn[3]);
            }
            #pragma unroll
            for (int r = 0; r < 4; ++r) { s.u.n.sPL[kg][r][j] = sr[r]; s.u.n.dPL[kg][r][j] = dtn[r]; }
        }
    }
    __syncthreads();

    // ---- combine + mask (192 lanes) ----
    if (tid < 4*NN) {
        int r = tid / NN, jj = tid % NN;
        int ni = n0 + r;
        float b1 = p.nr_b1[0];
        float ss = b1, do2 = 0.f;
        #pragma unroll
        for (int q = 0; q < 8; ++q) { ss += s.u.n.sPL[q][r][jj]; do2 += s.u.n.dPL[q][r][jj]; }
        float ddx = s.u.n.pjL[ni][0] - s.u.n.pjL[jj][0];
        float ddy = s.u.n.pjL[ni][1] - s.u.n.pjL[jj][1];
        float dist = sqrtf(ddx*ddx + ddy*ddy);
        bool ok = (s.u.n.pjL[ni][4] > 0.5f) && (s.u.n.pjL[jj][4] > 0.5f) &&
                  (dist <= RADIUS_C) && (jj != ni);
        s.u.n.lgN[r][jj] = ok ? fmaf(do2, RSQRT_H, ss) : -1e9f;
    }
    __syncthreads();

    // ---- nbr softmax: waves 0-3 handle rows 0-3 ----
    if (tid < 256) {
        int r = tid >> 6, l = tid & 63;
        float v = (l < NN) ? s.u.n.lgN[r][l] : -3.4e38f;
        #pragma unroll
        for (int o = 32; o > 0; o >>= 1) v = fmaxf(v, __shfl_xor(v, o));
        float e = (l < NN) ? expf(s.u.n.lgN[r][l] - v) : 0.f;
        float sm = e;
        #pragma unroll
        for (int o = 32; o > 0; o >>= 1) sm += __shfl_xor(sm, o);
        if (l < NN) s.u.n.lgN[r][l] = e / sm;
    }
    __syncthreads();
    if (tid < NN) {
        s.u.n.pN[tid] = make_float4(s.u.n.lgN[0][tid], s.u.n.lgN[1][tid],
                                    s.u.n.lgN[2][tid], s.u.n.lgN[3][tid]);
    }
    __syncthreads();

    // ---- nbr phase C: 4-way j-split (12 each) ----
    {
        int gq = tid >> 7, c = tid & 127;
        float a0=0.f, a1=0.f, a2=0.f, a3=0.f;
        for (int jj = gq*12; jj < gq*12 + 12; ++jj) {
            float av = p.a_emb[((size_t)(b*NN + jj)*TT + t)*HH + c];
            float4 pp4 = s.u.n.pN[jj];
            a0 = fmaf(pp4.x, av, a0); a1 = fmaf(pp4.y, av, a1);
            a2 = fmaf(pp4.z, av, a2); a3 = fmaf(pp4.w, av, a3);
        }
        s.pc[gq][0][c]=a0; s.pc[gq][1][c]=a1; s.pc[gq][2][c]=a2; s.pc[gq][3][c]=a3;
    }
    __syncthreads();
    {
        int r = tid >> 7, c = tid & 127;
        float v = s.pc[0][r][c] + s.pc[1][r][c] + s.pc[2][r][c] + s.pc[3][r][c];
        s.nctx[r][c] = v;
        p.nbr_ctx[(size_t)(row0 + r*TT)*HH + c] = v;
    }
    __syncthreads();   // u.n dead

    // ---- tau phase: pack xinT[k] = 4 rows per float4 ----
    if (tid < 3*HH) {
        int idx = tid;
        if (idx < HH) {
            s.u.t.xinT[idx] = s.aq4L[idx];
        } else if (idx < 2*HH) {
            int k = idx - HH;
            s.u.t.xinT[idx] = make_float4(s.mctx[0][k], s.mctx[1][k], s.mctx[2][k], s.mctx[3][k]);
        } else {
            int k = idx - 2*HH;
            s.u.t.xinT[idx] = make_float4(s.nctx[0][k], s.nctx[1][k], s.nctx[2][k], s.nctx[3][k]);
        }
    }
    __syncthreads();
    // layer0: 4-way k-split (96 each)
    {
        int h = tid >> 7, c = tid & 127;
        float acc[4] = {0,0,0,0};
        for (int k = h*96; k < h*96 + 96; ++k) {
            float wv = p.to_w0[k*HH + c];
            float4 x4 = s.u.t.xinT[k];
            acc[0]=fmaf(x4.x,wv,acc[0]); acc[1]=fmaf(x4.y,wv,acc[1]);
            acc[2]=fmaf(x4.z,wv,acc[2]); acc[3]=fmaf(x4.w,wv,acc[3]);
        }
        #pragma unroll
        for (int r = 0; r < 4; ++r) s.pc[h][r][c] = acc[r];
    }
    __syncthreads();
    {
        int r = tid >> 7, k = tid & 127;
        float v = s.pc[0][r][k] + s.pc[1][r][k] + s.pc[2][r][k] + s.pc[3][r][k] + p.to_b0[k];
        ((float*)&s.u.t.h1T[k])[r] = fmaxf(v, 0.f);
    }
    __syncthreads();
    // layer1: 2-way k-split; (kh, r, c2)
    {
        int kh = tid >> 8, rc = tid & 255;
        int r = rc >> 6, c2 = rc & 63;
        float acc = 0.f;
        for (int k = kh*64; k < kh*64 + 64; ++k)
            acc = fmaf(((const float*)&s.u.t.h1T[k])[r], p.to_w1[k*64 + c2], acc);
        s.pc[kh][r][c2] = acc;
    }
    __syncthreads();
    if (tid < 256) {
        int r = tid >> 6, c2 = tid & 63;
        int row = row0 + r*TT;
        float v = (s.pc[0][r][c2] + s.pc[1][r][c2] + p.to_b1[c2]) * p.amask[row];
        p.tau[(size_t)row*64 + c2] = v;
    }
}

extern "C" void kernel_launch(void* const* d_in, const int* in_sizes, int n_in,
                              void* d_out, int out_size, void* d_ws, size_t ws_size,
                              hipStream_t stream)
{
    P p;
    p.astate    = (const float*)d_in[0];
    p.amask     = (const float*)d_in[1];
    p.polylines = (const float*)d_in[2];
    p.poly_mask = (const float*)d_in[3];
    p.ptype     = (const int*)d_in[4];
    p.tlst      = (const int*)d_in[5];
    p.route     = (const int*)d_in[6];
    p.ae_w0 = (const float*)d_in[7];  p.ae_b0 = (const float*)d_in[8];
    p.ae_w1 = (const float*)d_in[9];  p.ae_b1 = (const float*)d_in[10];
    p.ae_w2 = (const float*)d_in[11]; p.ae_b2 = (const float*)d_in[12];
    p.mp_w0 = (const float*)d_in[13]; p.mp_b0 = (const float*)d_in[14];
    p.mp_w1 = (const float*)d_in[15]; p.mp_b1 = (const float*)d_in[16];
    p.type_emb  = (const float*)d_in[17];
    p.tl_emb    = (const float*)d_in[18];
    p.route_emb = (const float*)d_in[19];
    p.mo_w0 = (const float*)d_in[20]; p.mo_b0 = (const float*)d_in[21];
    p.mo_w1 = (const float*)d_in[22]; p.mo_b1 = (const float*)d_in[23];
    p.mr_w0 = (const float*)d_in[24]; p.mr_b0 = (const float*)d_in[25];
    p.mr_w1 = (const float*)d_in[26]; p.mr_b1 = (const float*)d_in[27];
    p.nr_w0 = (const float*)d_in[28]; p.nr_b0 = (const float*)d_in[29];
    p.nr_w1 = (const float*)d_in[30]; p.nr_b1 = (const float*)d_in[31];
    p.to_w0 = (const float*)d_in[32]; p.to_b0 = (const float*)d_in[33];
    p.to_w1 = (const float*)d_in[34]; p.to_b1 = (const float*)d_in[35];

    p.tau     = (float*)d_out;
    p.map_ctx = (float*)d_out + (size_t)NT*64;
    p.nbr_ctx = p.map_ctx + (size_t)NT*HH;

    float* ws    = (float*)d_ws;
    p.a_emb      = ws;                                   // NT*HH
    p.map_node   = p.a_emb + (size_t)NT*HH;              // B*M*HH
    p.map_nodeT  = p.map_node + (size_t)BB*MM*HH;        // B*HH*MM
    p.map_center = p.map_nodeT + (size_t)BB*MM*HH;       // B*M*2

    k_enc<<<BB*MM + NT/2, 256, 0, stream>>>(p);          // 384 + 1152 = 1536
    k_fat<<<BB*TT*12,     512, 0, stream>>>(p);          // 576
}